// Round 3
// baseline (397.948 us; speedup 1.0000x reference)
//
#include <hip/hip_runtime.h>

// Downsample1d: depthwise stride-2 FIR, taps [1/8, 3/8, 3/8, 1/8], reflect pad 1.
// x: [B=8, C=128, T=65536] fp32  ->  out: [8, 128, 32768] fp32
// out[t] = 0.125*(x[2t-1] + x[2t+2]) + 0.375*(x[2t] + x[2t+1])
// reflect: x[-1] -> x[1], x[T] -> x[T-2]

#define T_LEN   65536
#define TO_LEN  32768
#define ROWS    1024            // B*C
#define OPT     8               // outputs per thread
#define JPR     (TO_LEN / OPT)  // threads per row = 4096

typedef float vf4 __attribute__((ext_vector_type(4)));  // native vector: ok for nontemporal builtins

__global__ __launch_bounds__(256)
void ds1d_kernel(const float* __restrict__ x, float* __restrict__ out) {
    int g   = blockIdx.x * 256 + threadIdx.x;
    int row = g >> 12;            // g / JPR  (JPR = 4096 = 2^12)
    int j   = g & (JPR - 1);
    long long xbase = (long long)row * T_LEN;
    long long obase = (long long)row * TO_LEN;
    int i0 = j << 4;              // input start index (16 floats per thread)

    // four aligned 16B loads: x[i0 .. i0+15]
    const vf4* xv = (const vf4*)(x + xbase + i0);
    vf4 a = xv[0];
    vf4 b = xv[1];
    vf4 c = xv[2];
    vf4 d = xv[3];

    // boundary neighbors, branchless reflect (L1/L2 hits except at row edges)
    int im1  = (i0 == 0)          ? 1           : (i0 - 1);
    int ip16 = (i0 + 16 >= T_LEN) ? (T_LEN - 2) : (i0 + 16);
    float xm1  = x[xbase + im1];
    float xp16 = x[xbase + ip16];

    vf4 y0, y1;
    y0.x = 0.125f * (xm1 + a.z) + 0.375f * (a.x + a.y);
    y0.y = 0.125f * (a.y + b.x) + 0.375f * (a.z + a.w);
    y0.z = 0.125f * (a.w + b.z) + 0.375f * (b.x + b.y);
    y0.w = 0.125f * (b.y + c.x) + 0.375f * (b.z + b.w);
    y1.x = 0.125f * (b.w + c.z) + 0.375f * (c.x + c.y);
    y1.y = 0.125f * (c.y + d.x) + 0.375f * (c.z + c.w);
    y1.z = 0.125f * (c.w + d.z) + 0.375f * (d.x + d.y);
    y1.w = 0.125f * (d.y + xp16) + 0.375f * (d.z + d.w);

    vf4* ov = (vf4*)(out + obase + (j << 3));
    __builtin_nontemporal_store(y0, &ov[0]);
    __builtin_nontemporal_store(y1, &ov[1]);
}

extern "C" void kernel_launch(void* const* d_in, const int* in_sizes, int n_in,
                              void* d_out, int out_size, void* d_ws, size_t ws_size,
                              hipStream_t stream) {
    const float* x = (const float*)d_in[0];
    // d_in[1] is the fixed FIR taps [1/8,3/8,3/8,1/8]; hardcoded above.
    float* out = (float*)d_out;

    int total_threads = ROWS * JPR;          // 4,194,304
    int blocks = total_threads / 256;        // 16,384
    ds1d_kernel<<<blocks, 256, 0, stream>>>(x, out);
}